// Round 13
// baseline (259.479 us; speedup 1.0000x reference)
//
#include <hip/hip_runtime.h>
#include <hip/hip_bf16.h>

typedef __attribute__((ext_vector_type(8))) short bf16x8;
typedef __attribute__((ext_vector_type(4))) float f32x4;
typedef unsigned short u16;
typedef unsigned int u32;

#define EPS 1e-5f
#define CIN 96
#define HD 576
#define HW 3136
#define NB 32

// ---- fused-kernel LDS layout (bytes) ----
// No Xt stage (x fragments loaded direct from global); 32-channel chunks.
// Hc [32][HCS] + H2c [224][H2S] = 39,552 B <= 64 KiB -> 2 blocks/CU
// (m132: 64KB/block = 2 blocks/CU on gfx950; round 11 showed 75.5KB = 1).
#define HCS   338                       // Hc row stride (u16): dword stride 169 (odd) -> conflict-free dw reads
#define HC_OFF 0                        // [32][338] = 21,632 B
#define H2_OFF 21632                    // 16B aligned
#define H2S   40                        // H2c row stride (u16): 32 k + 8 pad; 80B rows, 16B aligned
#define SMEM_BYTES (H2_OFF + 224 * H2S * 2)   // 39,552

__device__ __forceinline__ u16 f2bf(float f) {
  u32 u = __builtin_bit_cast(u32, f);
  u32 r = u + 0x7fffu + ((u >> 16) & 1u);   // RNE
  return (u16)(r >> 16);
}
__device__ __forceinline__ float bf2f(u16 h) {
  return __builtin_bit_cast(float, (u32)h << 16);
}

// ---------------- kernel 0: weight conversion + BN folding ----------------
__global__ __launch_bounds__(256) void prep_kernel(
    const float* __restrict__ w1, const float* __restrict__ w2,
    const float* __restrict__ g1, const float* __restrict__ b1,
    const float* __restrict__ m1, const float* __restrict__ v1,
    const float* __restrict__ gdw, const float* __restrict__ bdw,
    const float* __restrict__ mdw, const float* __restrict__ vdw,
    const float* __restrict__ g2, const float* __restrict__ b2,
    const float* __restrict__ m2, const float* __restrict__ v2,
    u16* __restrict__ w1b, u16* __restrict__ w2b, float* __restrict__ bn)
{
  int i = blockIdx.x * 256 + threadIdx.x;
  if (i < HD * CIN) {
    w1b[i] = f2bf(w1[i]);
    w2b[i] = f2bf(w2[i]);
  }
  if (i < HD) {
    float s = g1[i] * rsqrtf(v1[i] + EPS);
    bn[i] = s;
    bn[HD + i] = b1[i] - m1[i] * s;
    float sd = gdw[i] * rsqrtf(vdw[i] + EPS);
    bn[2 * HD + i] = sd;
    bn[3 * HD + i] = bdw[i] - mdw[i] * sd;
  }
  if (i < CIN) {
    float s2 = g2[i] * rsqrtf(v2[i] + EPS);
    bn[4 * HD + i] = s2;
    bn[4 * HD + CIN + i] = b2[i] - m2[i] * s2;
  }
}

// ---------------- fused kernel: expand+BN+ReLU -> dw3x3+BN+ReLU -> proj+BN+res
// block = (batch b, 4 output rows). 448 threads = 7 waves. 18 chunks of 32
// hd-channels: expand (MFMA) -> Hc(LDS) -> dw (VALU, 1 item/thread) ->
// H2c(LDS) -> proj (MFMA, acc in VGPRs). x fragments direct from global
// (no Xt stage). 39.5 KB LDS -> 2 blocks/CU, all 448 blocks co-resident.
__global__ __launch_bounds__(448, 2) void fused_kernel(
    const float* __restrict__ x, const u16* __restrict__ w1b,
    const u16* __restrict__ w2b, const float* __restrict__ wdw,
    const float* __restrict__ bnp, float* __restrict__ out)
{
  extern __shared__ __align__(16) char smem[];
  u16* Hc  = (u16*)(smem + HC_OFF);     // [32][HCS]
  u16* H2c = (u16*)(smem + H2_OFF);     // [224][H2S]

  const int tid = threadIdx.x;
  const int r0  = blockIdx.x * 4;       // output rows r0..r0+3
  const int b   = blockIdx.y;
  const int l   = tid & 63;
  const int w   = tid >> 6;             // wave 0..6
  const int lr  = l & 15;               // fragment row (M or N index)
  const int kq  = l >> 4;               // 0..3
  const int kb  = kq * 8;               // k sub-offset within 32

  // ---- load expand B-fragments (x) DIRECT from global, convert to bf16.
  // lane groups of 16 read 64B-aligned contiguous segments (px = tile*16+lr).
  const float* xb = x + (size_t)b * CIN * HW;
  const int pbase = (r0 - 1) * 56;      // global px of halo row 0, col 0
  bf16x8 xf[3][3];                      // [tile][ks]
#pragma unroll
  for (int t = 0; t < 3; ++t) {
    int gpx = pbase + (w * 3 + t) * 16 + lr;
    gpx = gpx < 0 ? 0 : (gpx > HW - 1 ? HW - 1 : gpx);   // clamp (masked in dw)
    const float* xp = xb + gpx;
#pragma unroll
    for (int ks = 0; ks < 3; ++ks) {
      bf16x8 pk;
#pragma unroll
      for (int j = 0; j < 8; ++j)
        pk[j] = (short)f2bf(xp[(size_t)(ks * 32 + kq * 8 + j) * HW]);
      xf[t][ks] = pk;
    }
  }

  const int chl_dw = tid & 31;          // dw channel within chunk
  const int cg_dw  = tid >> 5;          // dw col-group 0..13 (448 = 32*14)
  f32x4 pacc[2][6] = {};                // proj accumulator [ntile][mtile]

  for (int kc = 0; kc < 18; ++kc) {
    const int ch0 = kc * 32;

    // ---- prefetch dw params for this chunk (latency hides under expand)
    const int gch_dw = ch0 + chl_dw;
    float wk[9];
#pragma unroll
    for (int k = 0; k < 9; ++k) wk[k] = wdw[gch_dw * 9 + k];
    const float sdw = bnp[2 * HD + gch_dw], hdw = bnp[3 * HD + gch_dw];

    // ======== expand: M=32 (2 mt), N=336 (3 tiles/wave), K=96 ========
    bf16x8 af[2][3];
#pragma unroll
    for (int mt = 0; mt < 2; ++mt)
#pragma unroll
      for (int ks = 0; ks < 3; ++ks)
        af[mt][ks] = *(const bf16x8*)&w1b[(size_t)(ch0 + mt * 16 + lr) * CIN + ks * 32 + kb];

    f32x4 bsc[2], bsh[2];               // BN1 scale/shift (global, L2-hot)
#pragma unroll
    for (int mt = 0; mt < 2; ++mt) {
      bsc[mt] = *(const f32x4*)&bnp[ch0 + mt * 16 + kq * 4];
      bsh[mt] = *(const f32x4*)&bnp[HD + ch0 + mt * 16 + kq * 4];
    }

#pragma unroll
    for (int t = 0; t < 3; ++t) {
      f32x4 ea[2] = {};
#pragma unroll
      for (int ks = 0; ks < 3; ++ks) {
        ea[0] = __builtin_amdgcn_mfma_f32_16x16x32_bf16(af[0][ks], xf[t][ks], ea[0], 0, 0, 0);
        ea[1] = __builtin_amdgcn_mfma_f32_16x16x32_bf16(af[1][ks], xf[t][ks], ea[1], 0, 0, 0);
      }
      // epilogue: BN1 + ReLU -> Hc[ch][hpx]
      const int hpx = (w * 3 + t) * 16 + lr;
#pragma unroll
      for (int mt = 0; mt < 2; ++mt)
#pragma unroll
        for (int i = 0; i < 4; ++i) {
          int chl = mt * 16 + kq * 4 + i;
          float v = fmaxf(ea[mt][i] * bsc[mt][i] + bsh[mt][i], 0.f);
          Hc[chl * HCS + hpx] = f2bf(v);
        }
    }
    __syncthreads();                    // Hc ready; prev H2c proj-reads drained

    // ======== dw 3x3: 448 items = 32 ch x 14 col-groups, 1/thread ========
    {
      const int c0 = cg_dw * 4;
      float win[6][8];
#pragma unroll
      for (int hr = 0; hr < 6; ++hr) {
        int grow = r0 - 1 + hr;
        bool rv = (grow >= 0) && (grow < 56);
        const u16* rp = &Hc[chl_dw * HCS + hr * 56];
#pragma unroll
        for (int k2 = 0; k2 < 4; ++k2) {
          int cb = c0 - 2 + k2 * 2;     // -2..56 (even); in-row pad covers cb=56
          u32 pr = (rv && cb >= 0) ? *(const u32*)(rp + cb) : 0u;
          win[hr][k2 * 2]     = bf2f((u16)pr);
          win[hr][k2 * 2 + 1] = bf2f((u16)(pr >> 16));
        }
        if (c0 + 4 >= 56) win[hr][6] = 0.f;   // right-edge col 56
      }
#pragma unroll
      for (int orr = 0; orr < 4; ++orr) {
        float a4[4] = {0.f, 0.f, 0.f, 0.f};
#pragma unroll
        for (int dy = 0; dy < 3; ++dy)
#pragma unroll
          for (int j = 0; j < 4; ++j)
#pragma unroll
            for (int dx = 0; dx < 3; ++dx)
              a4[j] += wk[dy * 3 + dx] * win[orr + dy][j + dx + 1];
#pragma unroll
        for (int j = 0; j < 4; ++j) {
          float v = fmaxf(a4[j] * sdw + hdw, 0.f);
          H2c[(orr * 56 + c0 + j) * H2S + chl_dw] = f2bf(v);
        }
      }
    }
    __syncthreads();                    // H2c ready; Hc reads drained

    // ======== proj accumulate: M=96 (6 mt), N: tiles {2w,2w+1}, K=32 ========
    bf16x8 pa[6];
#pragma unroll
    for (int mt = 0; mt < 6; ++mt)
      pa[mt] = *(const bf16x8*)&w2b[(size_t)(mt * 16 + lr) * HD + ch0 + kb];
#pragma unroll
    for (int ntl = 0; ntl < 2; ++ntl) {
      int pt = w * 2 + ntl;
      bf16x8 pb = *(const bf16x8*)&H2c[(pt * 16 + lr) * H2S + kb];
#pragma unroll
      for (int mt = 0; mt < 6; ++mt)
        pacc[ntl][mt] = __builtin_amdgcn_mfma_f32_16x16x32_bf16(pa[mt], pb, pacc[ntl][mt], 0, 0, 0);
    }
  }

  // ---- final epilogue: BN2 + residual, fp32 out
  const float* xr = x   + (size_t)b * CIN * HW + r0 * 56;
  float*       ob = out + (size_t)b * CIN * HW + r0 * 56;
#pragma unroll
  for (int mt = 0; mt < 6; ++mt) {
    f32x4 s2 = *(const f32x4*)&bnp[4 * HD + mt * 16 + kq * 4];
    f32x4 h2 = *(const f32x4*)&bnp[4 * HD + CIN + mt * 16 + kq * 4];
#pragma unroll
    for (int ntl = 0; ntl < 2; ++ntl) {
      int opx = (w * 2 + ntl) * 16 + lr;
#pragma unroll
      for (int i = 0; i < 4; ++i) {
        int c = mt * 16 + kq * 4 + i;
        float v = pacc[ntl][mt][i] * s2[i] + h2[i];
        size_t idx = (size_t)c * HW + opx;
        ob[idx] = v + xr[idx];
      }
    }
  }
}

// ---------------- launcher ------------------------------------------------
extern "C" void kernel_launch(void* const* d_in, const int* in_sizes, int n_in,
                              void* d_out, int out_size, void* d_ws, size_t ws_size,
                              hipStream_t stream) {
  const float* x   = (const float*)d_in[0];
  const float* w1  = (const float*)d_in[1];
  const float* g1  = (const float*)d_in[2];
  const float* b1  = (const float*)d_in[3];
  const float* m1  = (const float*)d_in[4];
  const float* v1  = (const float*)d_in[5];
  const float* wdw = (const float*)d_in[6];
  const float* gdw = (const float*)d_in[7];
  const float* bdw = (const float*)d_in[8];
  const float* mdw = (const float*)d_in[9];
  const float* vdw = (const float*)d_in[10];
  const float* w2  = (const float*)d_in[11];
  const float* g2  = (const float*)d_in[12];
  const float* b2  = (const float*)d_in[13];
  const float* m2  = (const float*)d_in[14];
  const float* v2  = (const float*)d_in[15];
  float* out = (float*)d_out;

  // workspace: w1b bf16 [576][96], w2b bf16 [96][576], bn f32 [2496]  (~231 KB)
  char* ws = (char*)d_ws;
  u16*   w1b = (u16*)ws;
  u16*   w2b = (u16*)(ws + 2 * (size_t)HD * CIN);
  float* bnp = (float*)(ws + 4 * (size_t)HD * CIN);

  prep_kernel<<<dim3((HD * CIN + 255) / 256), 256, 0, stream>>>(
      w1, w2, g1, b1, m1, v1, gdw, bdw, mdw, vdw, g2, b2, m2, v2, w1b, w2b, bnp);

  fused_kernel<<<dim3(14, NB), 448, SMEM_BYTES, stream>>>(x, w1b, w2b, wdw, bnp, out);
}

// Round 14
// 241.438 us; speedup vs baseline: 1.0747x; 1.0747x over previous
//
#include <hip/hip_runtime.h>
#include <hip/hip_bf16.h>

typedef __attribute__((ext_vector_type(8))) short bf16x8;
typedef __attribute__((ext_vector_type(4))) float f32x4;
typedef unsigned short u16;
typedef unsigned int u32;

#define EPS 1e-5f
#define CIN 96
#define HD 576
#define HW 3136
#define NB 32

// ---- fused-kernel LDS layout (bytes), 8-row strip, 768-thread block ----
// Hc [32 ch][HCS] (halo 10 rows = 560 px, padded tiles to 576) +
// H2c [448 px][H2S]. 72,832 B total, 1 block/CU (occupancy comes from
// 12 waves/block = 3/SIMD, the VGPR-cap sweet spot: arch+AGPR ~160 <= 170).
#define HCS   578                       // Hc row stride (u16): dword stride 289 (odd) -> conflict-free dw reads
#define HC_OFF 0                        // 32*578*2 = 36,992 B
#define H2_OFF 36992                    // 16B aligned
#define H2S   40                        // H2c row stride (u16): 32 k + 8 pad; proj b128 reads uniform 8 lanes/bank
#define SMEM_BYTES (H2_OFF + 448 * H2S * 2)   // 72,832

__device__ __forceinline__ u16 f2bf(float f) {
  u32 u = __builtin_bit_cast(u32, f);
  u32 r = u + 0x7fffu + ((u >> 16) & 1u);   // RNE
  return (u16)(r >> 16);
}
__device__ __forceinline__ float bf2f(u16 h) {
  return __builtin_bit_cast(float, (u32)h << 16);
}

// ---------------- kernel 0: weight conversion + BN folding ----------------
__global__ __launch_bounds__(256) void prep_kernel(
    const float* __restrict__ w1, const float* __restrict__ w2,
    const float* __restrict__ g1, const float* __restrict__ b1,
    const float* __restrict__ m1, const float* __restrict__ v1,
    const float* __restrict__ gdw, const float* __restrict__ bdw,
    const float* __restrict__ mdw, const float* __restrict__ vdw,
    const float* __restrict__ g2, const float* __restrict__ b2,
    const float* __restrict__ m2, const float* __restrict__ v2,
    u16* __restrict__ w1b, u16* __restrict__ w2b, float* __restrict__ bn)
{
  int i = blockIdx.x * 256 + threadIdx.x;
  if (i < HD * CIN) {
    w1b[i] = f2bf(w1[i]);
    w2b[i] = f2bf(w2[i]);
  }
  if (i < HD) {
    float s = g1[i] * rsqrtf(v1[i] + EPS);
    bn[i] = s;
    bn[HD + i] = b1[i] - m1[i] * s;
    float sd = gdw[i] * rsqrtf(vdw[i] + EPS);
    bn[2 * HD + i] = sd;
    bn[3 * HD + i] = bdw[i] - mdw[i] * sd;
  }
  if (i < CIN) {
    float s2 = g2[i] * rsqrtf(v2[i] + EPS);
    bn[4 * HD + i] = s2;
    bn[4 * HD + CIN + i] = b2[i] - m2[i] * s2;
  }
}

// ---------------- fused kernel: expand+BN+ReLU -> dw3x3+BN+ReLU -> proj+BN+res
// block = (batch b, 8 output rows). 768 threads = 12 waves (3/SIMD exactly).
// grid 7x32 = 224 blocks <= 256 CUs: SINGLE dispatch round. 18 chunks of 32
// hd-channels: expand (MFMA, 36 px-tiles = 12 waves x 3) -> Hc(LDS) ->
// dw (VALU, 448 active thr, rolling window) -> H2c(LDS) -> proj (MFMA,
// wave = (M-tile, N-half), pacc[14] in AGPR). x frags direct from global.
__global__ __launch_bounds__(768, 3) void fused_kernel(
    const float* __restrict__ x, const u16* __restrict__ w1b,
    const u16* __restrict__ w2b, const float* __restrict__ wdw,
    const float* __restrict__ bnp, float* __restrict__ out)
{
  extern __shared__ __align__(16) char smem[];
  u16* Hc  = (u16*)(smem + HC_OFF);     // [32][HCS]
  u16* H2c = (u16*)(smem + H2_OFF);     // [448][H2S]

  const int tid = threadIdx.x;
  const int r0  = blockIdx.x * 8;       // output rows r0..r0+7
  const int b   = blockIdx.y;
  const int l   = tid & 63;
  const int w   = tid >> 6;             // wave 0..11
  const int lr  = l & 15;               // fragment row (M or N index)
  const int kq  = l >> 4;               // 0..3
  const int kb  = kq * 8;               // k sub-offset within 32

  // ---- load expand B-fragments (x) DIRECT from global, convert to bf16.
  // halo = rows r0-1 .. r0+8 (10 rows = 560 px), padded to 576 px (36 tiles).
  const float* xb = x + (size_t)b * CIN * HW;
  const int pbase = (r0 - 1) * 56;      // global px of halo row 0, col 0
  bf16x8 xf[3][3];                      // [tile][ks]; tile tw = w*3+t
#pragma unroll
  for (int t = 0; t < 3; ++t) {
    int gpx = pbase + (w * 3 + t) * 16 + lr;
    gpx = gpx < 0 ? 0 : (gpx > HW - 1 ? HW - 1 : gpx);   // clamp (masked in dw)
    const float* xp = xb + gpx;
#pragma unroll
    for (int ks = 0; ks < 3; ++ks) {
      bf16x8 pk;
#pragma unroll
      for (int j = 0; j < 8; ++j)
        pk[j] = (short)f2bf(xp[(size_t)(ks * 32 + kq * 8 + j) * HW]);
      xf[t][ks] = pk;
    }
  }

  const bool dw_act = tid < 448;        // 32 ch x 14 col-groups
  const int chl_dw = tid & 31;
  const int cg_dw  = tid >> 5;          // 0..13 when active
  const int mi = w >> 1;                // proj M-tile 0..5
  const int nj = w & 1;                 // proj N-half 0..1
  f32x4 pacc[14] = {};                  // proj accumulator (AGPR, 56 regs)

  for (int kc = 0; kc < 18; ++kc) {
    const int ch0 = kc * 32;

    // ---- prefetch dw params (latency hides under expand); waves 7-11 skip
    float wk[9];
    float sdw = 0.f, hdw = 0.f;
    if (dw_act) {
      const int gch_dw = ch0 + chl_dw;
#pragma unroll
      for (int k = 0; k < 9; ++k) wk[k] = wdw[gch_dw * 9 + k];
      sdw = bnp[2 * HD + gch_dw];
      hdw = bnp[3 * HD + gch_dw];
    }

    // ======== expand: M=32 (2 mt), N=576 (3 tiles/wave), K=96 ========
    bf16x8 af[2][3];
#pragma unroll
    for (int mt = 0; mt < 2; ++mt)
#pragma unroll
      for (int ks = 0; ks < 3; ++ks)
        af[mt][ks] = *(const bf16x8*)&w1b[(size_t)(ch0 + mt * 16 + lr) * CIN + ks * 32 + kb];

    f32x4 bsc[2], bsh[2];               // BN1 scale/shift (global, L2-hot)
#pragma unroll
    for (int mt = 0; mt < 2; ++mt) {
      bsc[mt] = *(const f32x4*)&bnp[ch0 + mt * 16 + kq * 4];
      bsh[mt] = *(const f32x4*)&bnp[HD + ch0 + mt * 16 + kq * 4];
    }

#pragma unroll
    for (int t = 0; t < 3; ++t) {
      f32x4 ea[2] = {};
#pragma unroll
      for (int ks = 0; ks < 3; ++ks) {
        ea[0] = __builtin_amdgcn_mfma_f32_16x16x32_bf16(af[0][ks], xf[t][ks], ea[0], 0, 0, 0);
        ea[1] = __builtin_amdgcn_mfma_f32_16x16x32_bf16(af[1][ks], xf[t][ks], ea[1], 0, 0, 0);
      }
      const int hpx = (w * 3 + t) * 16 + lr;   // 0..575 < HCS=578
#pragma unroll
      for (int mt = 0; mt < 2; ++mt)
#pragma unroll
        for (int i = 0; i < 4; ++i) {
          int chl = mt * 16 + kq * 4 + i;
          float v = fmaxf(ea[mt][i] * bsc[mt][i] + bsh[mt][i], 0.f);
          Hc[chl * HCS + hpx] = f2bf(v);
        }
    }
    __syncthreads();                    // Hc ready; prev H2c proj-reads drained

    // ======== dw 3x3: 448 threads, each (ch, 4-col group) x 8 rows ========
    if (dw_act) {
      const int c0 = cg_dw * 4;
      const u16* hrow = &Hc[chl_dw * HCS];
      float wr[3][8];                   // rolling window, slot = hr % 3

#define LOADROW(slot, hr_)                                                  \
      {                                                                     \
        int grow = r0 - 1 + (hr_);                                          \
        bool rv = (unsigned)grow < 56u;                                     \
        const u16* rp = hrow + (hr_) * 56;                                  \
        _Pragma("unroll")                                                   \
        for (int k2 = 0; k2 < 4; ++k2) {                                    \
          int cb = c0 - 2 + k2 * 2;                                         \
          u32 pr = (rv && cb >= 0) ? *(const u32*)(rp + cb) : 0u;           \
          wr[slot][k2 * 2]     = bf2f((u16)pr);                             \
          wr[slot][k2 * 2 + 1] = bf2f((u16)(pr >> 16));                     \
        }                                                                   \
        if (c0 + 4 >= 56) wr[slot][6] = 0.f;                                \
      }

      LOADROW(0, 0)
      LOADROW(1, 1)
#pragma unroll
      for (int orr = 0; orr < 8; ++orr) {
        LOADROW((orr + 2) % 3, orr + 2)
        float a4[4] = {0.f, 0.f, 0.f, 0.f};
#pragma unroll
        for (int dy = 0; dy < 3; ++dy) {
          const int slot = (orr + dy) % 3;
#pragma unroll
          for (int j = 0; j < 4; ++j)
#pragma unroll
            for (int dx = 0; dx < 3; ++dx)
              a4[j] += wk[dy * 3 + dx] * wr[slot][j + dx + 1];
        }
#pragma unroll
        for (int j = 0; j < 4; ++j) {
          float v = fmaxf(a4[j] * sdw + hdw, 0.f);
          H2c[(orr * 56 + c0 + j) * H2S + chl_dw] = f2bf(v);
        }
      }
#undef LOADROW
    }
    __syncthreads();                    // H2c ready; Hc reads drained

    // ======== proj: wave = (M-tile mi, N-half nj); 14 N-tiles; K=32 ========
    bf16x8 pa = *(const bf16x8*)&w2b[(size_t)(mi * 16 + lr) * HD + ch0 + kb];
#pragma unroll
    for (int t = 0; t < 14; ++t) {
      bf16x8 pb = *(const bf16x8*)&H2c[((nj * 14 + t) * 16 + lr) * H2S + kb];
      pacc[t] = __builtin_amdgcn_mfma_f32_16x16x32_bf16(pa, pb, pacc[t], 0, 0, 0);
    }
  }

  // ---- final epilogue: BN2 + residual, fp32 out (8 rows, no masking: 7*8=56)
  const float* xr = x   + (size_t)b * CIN * HW + r0 * 56;
  float*       ob = out + (size_t)b * CIN * HW + r0 * 56;
  f32x4 s2 = *(const f32x4*)&bnp[4 * HD + mi * 16 + kq * 4];
  f32x4 h2 = *(const f32x4*)&bnp[4 * HD + CIN + mi * 16 + kq * 4];
#pragma unroll
  for (int t = 0; t < 14; ++t) {
    int opx = (nj * 14 + t) * 16 + lr;  // 0..447
#pragma unroll
    for (int i = 0; i < 4; ++i) {
      int c = mi * 16 + kq * 4 + i;
      float v = pacc[t][i] * s2[i] + h2[i];
      size_t idx = (size_t)c * HW + opx;
      ob[idx] = v + xr[idx];
    }
  }
}

// ---------------- launcher ------------------------------------------------
extern "C" void kernel_launch(void* const* d_in, const int* in_sizes, int n_in,
                              void* d_out, int out_size, void* d_ws, size_t ws_size,
                              hipStream_t stream) {
  const float* x   = (const float*)d_in[0];
  const float* w1  = (const float*)d_in[1];
  const float* g1  = (const float*)d_in[2];
  const float* b1  = (const float*)d_in[3];
  const float* m1  = (const float*)d_in[4];
  const float* v1  = (const float*)d_in[5];
  const float* wdw = (const float*)d_in[6];
  const float* gdw = (const float*)d_in[7];
  const float* bdw = (const float*)d_in[8];
  const float* mdw = (const float*)d_in[9];
  const float* vdw = (const float*)d_in[10];
  const float* w2  = (const float*)d_in[11];
  const float* g2  = (const float*)d_in[12];
  const float* b2  = (const float*)d_in[13];
  const float* m2  = (const float*)d_in[14];
  const float* v2  = (const float*)d_in[15];
  float* out = (float*)d_out;

  // workspace: w1b bf16 [576][96], w2b bf16 [96][576], bn f32 [2496]  (~231 KB)
  char* ws = (char*)d_ws;
  u16*   w1b = (u16*)ws;
  u16*   w2b = (u16*)(ws + 2 * (size_t)HD * CIN);
  float* bnp = (float*)(ws + 4 * (size_t)HD * CIN);

  (void)hipFuncSetAttribute((const void*)fused_kernel,
                            hipFuncAttributeMaxDynamicSharedMemorySize, SMEM_BYTES);

  prep_kernel<<<dim3((HD * CIN + 255) / 256), 256, 0, stream>>>(
      w1, w2, g1, b1, m1, v1, gdw, bdw, mdw, vdw, g2, b2, m2, v2, w1b, w2b, bnp);

  fused_kernel<<<dim3(7, NB), 768, SMEM_BYTES, stream>>>(x, w1b, w2b, wdw, bnp, out);
}